// Round 1
// baseline (1494.126 us; speedup 1.0000x reference)
//
#include <hip/hip_runtime.h>
#include <hip/hip_bf16.h>

#define DIM 128

// ---------------------------------------------------------------------------
// Kernel 1: degree computation.  deg_out[src[e]] += 1, deg_in[dst[e]] += 1
// ---------------------------------------------------------------------------
__global__ __launch_bounds__(256) void deg_kernel(const int* __restrict__ src,
                                                  const int* __restrict__ dst,
                                                  float* __restrict__ deg_out,
                                                  float* __restrict__ deg_in,
                                                  int n_edges) {
    int e = blockIdx.x * 256 + threadIdx.x;
    if (e < n_edges) {
        atomicAdd(&deg_out[src[e]], 1.0f);
        atomicAdd(&deg_in[dst[e]], 1.0f);
    }
}

// ---------------------------------------------------------------------------
// Kernel 2: scatter-SpMM.  out[dst,:] += x[src,:] * rsqrt(max(deg_out[src],1))
// 32 threads per edge, float4 per thread (128 dims), scalar f32 atomics.
// ---------------------------------------------------------------------------
__global__ __launch_bounds__(256) void scatter_kernel(const float* __restrict__ x,
                                                      const int* __restrict__ src,
                                                      const int* __restrict__ dst,
                                                      const float* __restrict__ deg_out,
                                                      float* __restrict__ agg,
                                                      int n_edges) {
    int idx  = blockIdx.x * 256 + threadIdx.x;
    int e    = idx >> 5;        // 32 threads per edge
    int lane = idx & 31;
    if (e >= n_edges) return;
    int s = src[e];
    int t = dst[e];
    float ns = rsqrtf(fmaxf(deg_out[s], 1.0f));
    const float4* xr = reinterpret_cast<const float4*>(x + (size_t)s * DIM);
    float4 v = xr[lane];
    float* o = agg + (size_t)t * DIM + lane * 4;
    atomicAdd(o + 0, v.x * ns);
    atomicAdd(o + 1, v.y * ns);
    atomicAdd(o + 2, v.z * ns);
    atomicAdd(o + 3, v.w * ns);
}

// ---------------------------------------------------------------------------
// Kernel 3: in-place per-row scale + GEMM + bias.
// out[r,:] = (out[r,:] * rsqrt(max(deg_in[r],1))) @ W + b
// 128 threads/block; thread t holds W[:,t] in 128 VGPRs (W read once/block);
// the h row is broadcast from LDS (conflict-free).  Row-local => in-place safe.
// ---------------------------------------------------------------------------
__global__ __launch_bounds__(128) void scale_gemm_kernel(float* __restrict__ out,
                                                         const float* __restrict__ deg_in,
                                                         const float* __restrict__ Wg,
                                                         const float* __restrict__ bg,
                                                         int n_nodes) {
    int t = threadIdx.x;
    float wcol[DIM];
#pragma unroll
    for (int k = 0; k < DIM; ++k) wcol[k] = Wg[k * DIM + t];   // coalesced per k
    float bias = bg[t];
    __shared__ float h[DIM];
    for (int r = blockIdx.x; r < n_nodes; r += gridDim.x) {
        float nd = rsqrtf(fmaxf(deg_in[r], 1.0f));
        float v  = out[(size_t)r * DIM + t] * nd;
        __syncthreads();                 // protect h from previous iteration's readers
        h[t] = v;
        __syncthreads();
        float acc = bias;
#pragma unroll
        for (int k = 0; k < DIM; ++k) acc = fmaf(h[k], wcol[k], acc);
        out[(size_t)r * DIM + t] = acc;
    }
}

extern "C" void kernel_launch(void* const* d_in, const int* in_sizes, int n_in,
                              void* d_out, int out_size, void* d_ws, size_t ws_size,
                              hipStream_t stream) {
    const float* x   = (const float*)d_in[0];
    const int*   src = (const int*)d_in[1];
    const int*   dst = (const int*)d_in[2];
    const float* W   = (const float*)d_in[3];
    const float* b   = (const float*)d_in[4];
    float* out = (float*)d_out;

    const int n_nodes = in_sizes[0] / DIM;
    const int n_edges = in_sizes[1];

    // ws layout: deg_out [n_nodes] f32 | deg_in [n_nodes] f32
    float* deg_out = (float*)d_ws;
    float* deg_in  = deg_out + n_nodes;

    // Zero accumulators (harness poisons d_out/d_ws; we own the init).
    hipMemsetAsync(d_out, 0, (size_t)out_size * sizeof(float), stream);
    hipMemsetAsync(d_ws, 0, (size_t)2 * n_nodes * sizeof(float), stream);

    // 1) degrees
    {
        int grid = (n_edges + 255) / 256;
        deg_kernel<<<grid, 256, 0, stream>>>(src, dst, deg_out, deg_in, n_edges);
    }
    // 2) scatter h[src] into out[dst]
    {
        long long threads = (long long)n_edges * 32;
        int grid = (int)((threads + 255) / 256);
        scatter_kernel<<<grid, 256, 0, stream>>>(x, src, dst, deg_out, out, n_edges);
    }
    // 3) in-place scale + GEMM + bias
    {
        scale_gemm_kernel<<<2048, 128, 0, stream>>>(out, deg_in, W, b, n_nodes);
    }
}

// Round 2
// 310.028 us; speedup vs baseline: 4.8193x; 4.8193x over previous
//
#include <hip/hip_runtime.h>
#include <hip/hip_bf16.h>

#define DIM 128

// ---------------------------------------------------------------------------
// Kernel 1: int degree histogram.
// ---------------------------------------------------------------------------
__global__ __launch_bounds__(256) void deg_kernel(const int* __restrict__ src,
                                                  const int* __restrict__ dst,
                                                  int* __restrict__ deg_out,
                                                  int* __restrict__ deg_in,
                                                  int n_edges) {
    int e = blockIdx.x * 256 + threadIdx.x;
    if (e < n_edges) {
        atomicAdd(&deg_out[src[e]], 1);
        atomicAdd(&deg_in[dst[e]], 1);
    }
}

// ---------------------------------------------------------------------------
// Kernel 2: norm_src[i] = rsqrt(max(deg_out[i],1))
// ---------------------------------------------------------------------------
__global__ __launch_bounds__(256) void norm_kernel(const int* __restrict__ deg_out,
                                                   float* __restrict__ norm_src,
                                                   int n_nodes) {
    int i = blockIdx.x * 256 + threadIdx.x;
    if (i < n_nodes) norm_src[i] = rsqrtf(fmaxf((float)deg_out[i], 1.0f));
}

// ---------------------------------------------------------------------------
// Kernel 3: single-block exclusive scan of deg_in -> offs[0..n]  (offs[0]=0,
// offs[i+1]=inclusive sum).  1024 threads = 16 waves; wave shfl-scan + LDS.
// ---------------------------------------------------------------------------
__global__ __launch_bounds__(1024) void scan_kernel(const int* __restrict__ deg,
                                                    int* __restrict__ offs, int n) {
    __shared__ int wtot[16];
    __shared__ int carry;
    const int lane = threadIdx.x & 63;
    const int wid  = threadIdx.x >> 6;
    if (threadIdx.x == 0) { carry = 0; offs[0] = 0; }
    __syncthreads();
    for (int base = 0; base < n; base += 1024) {
        int i = base + threadIdx.x;
        int v = (i < n) ? deg[i] : 0;
        // wave64 inclusive scan
        int sc = v;
#pragma unroll
        for (int off = 1; off < 64; off <<= 1) {
            int t = __shfl_up(sc, off);
            if (lane >= off) sc += t;
        }
        if (lane == 63) wtot[wid] = sc;
        __syncthreads();
        if (threadIdx.x == 0) {
            int run = carry;
#pragma unroll
            for (int k = 0; k < 16; ++k) { int t = wtot[k]; wtot[k] = run; run += t; }
            carry = run;
        }
        __syncthreads();
        int incl = wtot[wid] + sc;
        if (i < n) offs[i + 1] = incl;
        __syncthreads();   // protect wtot/carry before next chunk overwrites
    }
}

// ---------------------------------------------------------------------------
// Kernel 4: bucket fill.  esrc[pos]=src[e], enrm[pos]=norm_src[src[e]]
// ---------------------------------------------------------------------------
__global__ __launch_bounds__(256) void fill_kernel(const int* __restrict__ src,
                                                   const int* __restrict__ dst,
                                                   const int* __restrict__ offs,
                                                   int* __restrict__ cursor,
                                                   const float* __restrict__ norm_src,
                                                   int* __restrict__ esrc,
                                                   float* __restrict__ enrm,
                                                   int n_edges) {
    int e = blockIdx.x * 256 + threadIdx.x;
    if (e < n_edges) {
        int t = dst[e];
        int s = src[e];
        int pos = offs[t] + atomicAdd(&cursor[t], 1);
        esrc[pos] = s;
        enrm[pos] = norm_src[s];
    }
}

// ---------------------------------------------------------------------------
// Kernel 5: gather-SpMM.  One wave (64 lanes) per dst node, float2 per lane.
// out[r,:] = norm_dst[r] * sum_{e in bucket(r)} x[esrc[e],:] * enrm[e]
// No float atomics; every output row written exactly once.
// ---------------------------------------------------------------------------
__global__ __launch_bounds__(256) void gather_kernel(const float* __restrict__ x,
                                                     const int* __restrict__ esrc,
                                                     const float* __restrict__ enrm,
                                                     const int* __restrict__ offs,
                                                     const int* __restrict__ deg_in,
                                                     float* __restrict__ out,
                                                     int n_nodes) {
    int node = blockIdx.x * 4 + (threadIdx.x >> 6);
    if (node >= n_nodes) return;
    int lane = threadIdx.x & 63;
    int beg = offs[node];
    int end = offs[node + 1];
    const float2* xp = reinterpret_cast<const float2*>(x);
    float ax = 0.0f, ay = 0.0f;
    for (int j = beg; j < end; ++j) {
        int s = esrc[j];
        float ns = enrm[j];
        float2 v = xp[(size_t)s * 64 + lane];
        ax = fmaf(v.x, ns, ax);
        ay = fmaf(v.y, ns, ay);
    }
    float nd = rsqrtf(fmaxf((float)deg_in[node], 1.0f));
    float2 r; r.x = ax * nd; r.y = ay * nd;
    reinterpret_cast<float2*>(out)[(size_t)node * 64 + lane] = r;
}

// ---------------------------------------------------------------------------
// Kernel 6: in-place row GEMM + bias.  out[r,:] = out[r,:] @ W + b
// Thread t holds W[:,t] in 128 VGPRs; h row broadcast from LDS.
// ---------------------------------------------------------------------------
__global__ __launch_bounds__(128) void gemm_kernel(float* __restrict__ out,
                                                   const float* __restrict__ Wg,
                                                   const float* __restrict__ bg,
                                                   int n_nodes) {
    int t = threadIdx.x;
    float wcol[DIM];
#pragma unroll
    for (int k = 0; k < DIM; ++k) wcol[k] = Wg[k * DIM + t];
    float bias = bg[t];
    __shared__ float h[DIM];
    for (int r = blockIdx.x; r < n_nodes; r += gridDim.x) {
        float v = out[(size_t)r * DIM + t];
        __syncthreads();
        h[t] = v;
        __syncthreads();
        float acc = bias;
#pragma unroll
        for (int k = 0; k < DIM; ++k) acc = fmaf(h[k], wcol[k], acc);
        out[(size_t)r * DIM + t] = acc;
    }
}

extern "C" void kernel_launch(void* const* d_in, const int* in_sizes, int n_in,
                              void* d_out, int out_size, void* d_ws, size_t ws_size,
                              hipStream_t stream) {
    const float* x   = (const float*)d_in[0];
    const int*   src = (const int*)d_in[1];
    const int*   dst = (const int*)d_in[2];
    const float* W   = (const float*)d_in[3];
    const float* b   = (const float*)d_in[4];
    float* out = (float*)d_out;

    const int n_nodes = in_sizes[0] / DIM;
    const int n_edges = in_sizes[1];

    // ws layout (all 4B elems):
    // [deg_out N][deg_in N][cursor N] (zeroed together) [offs N+1][norm_src N][esrc E][enrm E]
    int*   deg_out  = (int*)d_ws;
    int*   deg_in   = deg_out + n_nodes;
    int*   cursor   = deg_in + n_nodes;
    int*   offs     = cursor + n_nodes;
    float* norm_src = (float*)(offs + n_nodes + 1);
    int*   esrc     = (int*)(norm_src + n_nodes);
    float* enrm     = (float*)(esrc + n_edges);

    hipMemsetAsync(d_ws, 0, (size_t)3 * n_nodes * sizeof(int), stream);

    int egrid = (n_edges + 255) / 256;
    int ngrid = (n_nodes + 255) / 256;

    deg_kernel<<<egrid, 256, 0, stream>>>(src, dst, deg_out, deg_in, n_edges);
    norm_kernel<<<ngrid, 256, 0, stream>>>(deg_out, norm_src, n_nodes);
    scan_kernel<<<1, 1024, 0, stream>>>(deg_in, offs, n_nodes);
    fill_kernel<<<egrid, 256, 0, stream>>>(src, dst, offs, cursor, norm_src,
                                           esrc, enrm, n_edges);
    gather_kernel<<<(n_nodes + 3) / 4, 256, 0, stream>>>(x, esrc, enrm, offs,
                                                         deg_in, out, n_nodes);
    gemm_kernel<<<2048, 128, 0, stream>>>(out, W, b, n_nodes);
}

// Round 3
// 239.193 us; speedup vs baseline: 6.2465x; 1.2961x over previous
//
#include <hip/hip_runtime.h>
#include <hip/hip_bf16.h>

#define DIM 128
#define BM  64

// ---------------------------------------------------------------------------
// K1: int degree histogram.
// ---------------------------------------------------------------------------
__global__ __launch_bounds__(256) void deg_kernel(const int* __restrict__ src,
                                                  const int* __restrict__ dst,
                                                  int* __restrict__ deg_out,
                                                  int* __restrict__ deg_in,
                                                  int n_edges) {
    int e = blockIdx.x * 256 + threadIdx.x;
    if (e < n_edges) {
        atomicAdd(&deg_out[src[e]], 1);
        atomicAdd(&deg_in[dst[e]], 1);
    }
}

// ---------------------------------------------------------------------------
// K2: parallel exclusive scan (block-redundant prefix).  Block b re-sums
// deg[0 .. b*1024) (cheap, coalesced, ~1.2M total reads), then shfl-scans its
// own 1024-chunk.  offs[0]=0, offs[i+1]=inclusive sum.
// ---------------------------------------------------------------------------
__global__ __launch_bounds__(1024) void scan_kernel(const int* __restrict__ deg,
                                                    int* __restrict__ offs, int n) {
    __shared__ int w1[16], w2[16];
    const int tid = threadIdx.x, lane = tid & 63, wid = tid >> 6;
    const int base = blockIdx.x * 1024;

    // prefix = sum of everything before this chunk
    int part = 0;
    for (int i = tid; i < base; i += 1024) part += deg[i];
#pragma unroll
    for (int o = 32; o; o >>= 1) part += __shfl_xor(part, o);
    if (lane == 0) w1[wid] = part;
    __syncthreads();
    int prefix = 0;
#pragma unroll
    for (int k = 0; k < 16; ++k) prefix += w1[k];

    // local inclusive scan of this chunk
    int i = base + tid;
    int v = (i < n) ? deg[i] : 0;
    int sc = v;
#pragma unroll
    for (int o = 1; o < 64; o <<= 1) {
        int t = __shfl_up(sc, o);
        if (lane >= o) sc += t;
    }
    if (lane == 63) w2[wid] = sc;
    __syncthreads();
    int wpre = 0;
    for (int k = 0; k < wid; ++k) wpre += w2[k];
    if (i < n) offs[i + 1] = prefix + wpre + sc;
    if (base == 0 && tid == 0) offs[0] = 0;
}

// ---------------------------------------------------------------------------
// K3: bucket fill -> packed edge records {src, norm_src} (one 8B store/edge).
// ---------------------------------------------------------------------------
__global__ __launch_bounds__(256) void fill_kernel(const int* __restrict__ src,
                                                   const int* __restrict__ dst,
                                                   const int* __restrict__ offs,
                                                   int* __restrict__ cursor,
                                                   const int* __restrict__ deg_out,
                                                   int2* __restrict__ epk,
                                                   int n_edges) {
    int e = blockIdx.x * 256 + threadIdx.x;
    if (e >= n_edges) return;
    int t = dst[e];
    int s = src[e];
    int pos = offs[t] + atomicAdd(&cursor[t], 1);
    float ns = rsqrtf(fmaxf((float)deg_out[s], 1.0f));
    int2 p;
    p.x = s;
    p.y = __float_as_int(ns);
    epk[pos] = p;
}

// ---------------------------------------------------------------------------
// K4: gather-SpMM.  One wave per dst node, float2 per lane, edge loop
// unrolled x4 with independent accumulators to break the load-latency chain.
// ---------------------------------------------------------------------------
__global__ __launch_bounds__(256) void gather_kernel(const float* __restrict__ x,
                                                     const int2* __restrict__ epk,
                                                     const int* __restrict__ offs,
                                                     const int* __restrict__ deg_in,
                                                     float* __restrict__ out,
                                                     int n_nodes) {
    int node = blockIdx.x * 4 + (threadIdx.x >> 6);
    if (node >= n_nodes) return;
    int lane = threadIdx.x & 63;
    int j   = offs[node];
    int end = offs[node + 1];
    const float2* xp = reinterpret_cast<const float2*>(x);
    float ax0 = 0, ay0 = 0, ax1 = 0, ay1 = 0;
    float ax2 = 0, ay2 = 0, ax3 = 0, ay3 = 0;
    for (; j + 3 < end; j += 4) {
        int2 p0 = epk[j], p1 = epk[j + 1], p2 = epk[j + 2], p3 = epk[j + 3];
        float2 v0 = xp[(size_t)p0.x * 64 + lane];
        float2 v1 = xp[(size_t)p1.x * 64 + lane];
        float2 v2 = xp[(size_t)p2.x * 64 + lane];
        float2 v3 = xp[(size_t)p3.x * 64 + lane];
        float n0 = __int_as_float(p0.y), n1 = __int_as_float(p1.y);
        float n2 = __int_as_float(p2.y), n3 = __int_as_float(p3.y);
        ax0 = fmaf(v0.x, n0, ax0); ay0 = fmaf(v0.y, n0, ay0);
        ax1 = fmaf(v1.x, n1, ax1); ay1 = fmaf(v1.y, n1, ay1);
        ax2 = fmaf(v2.x, n2, ax2); ay2 = fmaf(v2.y, n2, ay2);
        ax3 = fmaf(v3.x, n3, ax3); ay3 = fmaf(v3.y, n3, ay3);
    }
    for (; j < end; ++j) {
        int2 p = epk[j];
        float2 v = xp[(size_t)p.x * 64 + lane];
        float ns = __int_as_float(p.y);
        ax0 = fmaf(v.x, ns, ax0); ay0 = fmaf(v.y, ns, ay0);
    }
    float nd = rsqrtf(fmaxf((float)deg_in[node], 1.0f));
    float2 r;
    r.x = (ax0 + ax1 + ax2 + ax3) * nd;
    r.y = (ay0 + ay1 + ay2 + ay3) * nd;
    reinterpret_cast<float2*>(out)[(size_t)node * 64 + lane] = r;
}

// ---------------------------------------------------------------------------
// K5: tiled fp32 GEMM + bias, in-place on out.  BM=64 rows x 128 cols, K=128.
// A tile staged TRANSPOSED in LDS (As[k][r], padded), W tile raw (Ws[k][c]).
// 256 threads, each computes a 4x8 micro-tile => 32 FMA per k per thread.
// In-place safe: all reads of this block's rows complete (into LDS) before
// any write; blocks own disjoint row ranges.
// ---------------------------------------------------------------------------
__global__ __launch_bounds__(256) void gemm_kernel(float* __restrict__ out,
                                                   const float* __restrict__ Wg,
                                                   const float* __restrict__ bg,
                                                   int n_nodes) {
    __shared__ float As[DIM][BM + 1];   // 128 x 65 f32 = 33.3 KB
    __shared__ float Ws[DIM][DIM];      // 64 KB
    const int tid = threadIdx.x;
    const int r0  = blockIdx.x * BM;

    // stage W: 4096 float4 / 256 threads = 16 each, straight copy
    {
        const float4* wsrc = reinterpret_cast<const float4*>(Wg);
        float4* wdst = reinterpret_cast<float4*>(&Ws[0][0]);
#pragma unroll
        for (int i = 0; i < 16; ++i) wdst[tid + i * 256] = wsrc[tid + i * 256];
    }
    // stage A transposed: 64 rows x 32 float4 = 2048 float4 / 256 threads = 8
    {
#pragma unroll
        for (int i = 0; i < 8; ++i) {
            int linear = tid + i * 256;       // 0..2047
            int r  = linear >> 5;             // row within tile
            int k4 = linear & 31;             // float4 index along k
            int row = r0 + r;
            float4 v = (row < n_nodes)
                         ? reinterpret_cast<const float4*>(out)[(size_t)row * 32 + k4]
                         : make_float4(0.f, 0.f, 0.f, 0.f);
            As[k4 * 4 + 0][r] = v.x;
            As[k4 * 4 + 1][r] = v.y;
            As[k4 * 4 + 2][r] = v.z;
            As[k4 * 4 + 3][r] = v.w;
        }
    }
    __syncthreads();

    const int cx = tid & 15;   // col group: cols cx*8 .. cx*8+7
    const int ry = tid >> 4;   // row group: rows ry*4 .. ry*4+3
    float acc[4][8];
#pragma unroll
    for (int rr = 0; rr < 4; ++rr)
#pragma unroll
        for (int cc = 0; cc < 8; ++cc) acc[rr][cc] = 0.f;

#pragma unroll 8
    for (int k = 0; k < DIM; ++k) {
        float4 a  = *reinterpret_cast<const float4*>(&As[k][ry * 4]);
        float4 b0 = *reinterpret_cast<const float4*>(&Ws[k][cx * 8]);
        float4 b1 = *reinterpret_cast<const float4*>(&Ws[k][cx * 8 + 4]);
        float av[4] = {a.x, a.y, a.z, a.w};
        float bv[8] = {b0.x, b0.y, b0.z, b0.w, b1.x, b1.y, b1.z, b1.w};
#pragma unroll
        for (int rr = 0; rr < 4; ++rr)
#pragma unroll
            for (int cc = 0; cc < 8; ++cc)
                acc[rr][cc] = fmaf(av[rr], bv[cc], acc[rr][cc]);
    }

    float bv[8];
#pragma unroll
    for (int cc = 0; cc < 8; ++cc) bv[cc] = bg[cx * 8 + cc];
#pragma unroll
    for (int rr = 0; rr < 4; ++rr) {
        int row = r0 + ry * 4 + rr;
        if (row >= n_nodes) continue;
        float4 o0, o1;
        o0.x = acc[rr][0] + bv[0]; o0.y = acc[rr][1] + bv[1];
        o0.z = acc[rr][2] + bv[2]; o0.w = acc[rr][3] + bv[3];
        o1.x = acc[rr][4] + bv[4]; o1.y = acc[rr][5] + bv[5];
        o1.z = acc[rr][6] + bv[6]; o1.w = acc[rr][7] + bv[7];
        float4* op = reinterpret_cast<float4*>(out + (size_t)row * DIM + cx * 8);
        op[0] = o0;
        op[1] = o1;
    }
}

extern "C" void kernel_launch(void* const* d_in, const int* in_sizes, int n_in,
                              void* d_out, int out_size, void* d_ws, size_t ws_size,
                              hipStream_t stream) {
    const float* x   = (const float*)d_in[0];
    const int*   src = (const int*)d_in[1];
    const int*   dst = (const int*)d_in[2];
    const float* W   = (const float*)d_in[3];
    const float* b   = (const float*)d_in[4];
    float* out = (float*)d_out;

    const int n_nodes = in_sizes[0] / DIM;
    const int n_edges = in_sizes[1];

    // ws layout (4B elems):
    // [deg_out N][deg_in N][cursor N] (zeroed) [offs N+1][epk 2E]
    int*  deg_out = (int*)d_ws;
    int*  deg_in  = deg_out + n_nodes;
    int*  cursor  = deg_in + n_nodes;
    int*  offs    = cursor + n_nodes;
    int2* epk     = (int2*)(offs + n_nodes + 1);

    hipMemsetAsync(d_ws, 0, (size_t)3 * n_nodes * sizeof(int), stream);

    int egrid = (n_edges + 255) / 256;

    deg_kernel<<<egrid, 256, 0, stream>>>(src, dst, deg_out, deg_in, n_edges);
    scan_kernel<<<(n_nodes + 1023) / 1024, 1024, 0, stream>>>(deg_in, offs, n_nodes);
    fill_kernel<<<egrid, 256, 0, stream>>>(src, dst, offs, cursor, deg_out, epk, n_edges);
    gather_kernel<<<(n_nodes + 3) / 4, 256, 0, stream>>>(x, epk, offs, deg_in, out, n_nodes);
    gemm_kernel<<<(n_nodes + BM - 1) / BM, 256, 0, stream>>>(out, W, b, n_nodes);
}